// Round 3
// baseline (119.539 us; speedup 1.0000x reference)
//
#include <hip/hip_runtime.h>

// Always (smoothed-min sliding window, W=16) over [B,T,D] fp32, two traces.
// out[b,t,d] = -log( sum_{j=0..15} exp(-5 x[b, max(t-15+j,0), d]) ) / 5
//
// R3: same van Herk float4 scheme as R2, but with the register budget
// opened up (__launch_bounds__(256,2) -> up to 256 VGPR) and ALL 48 float4
// loads per chunk issued up-front into distinct registers so the wave has
// 48 KB of memory traffic in flight (R2's 48-VGPR allocation serialized
// the loads into ~3-deep chains -> latency-bound on cold L3).

#define TT     8192
#define DD     64
#define BB     16
#define LCH    32            // t-steps per lane
#define CHUNKS (TT / LCH)    // 256

__device__ __forceinline__ float4 exp4n(float4 v) {
    float4 r;
    r.x = __expf(-5.0f * v.x);
    r.y = __expf(-5.0f * v.y);
    r.z = __expf(-5.0f * v.z);
    r.w = __expf(-5.0f * v.w);
    return r;
}
__device__ __forceinline__ float4 add4(float4 a, float4 b) {
    return make_float4(a.x + b.x, a.y + b.y, a.z + b.z, a.w + b.w);
}
__device__ __forceinline__ float4 mlog4(float4 v) {
    float4 r;
    r.x = -0.2f * __logf(v.x);
    r.y = -0.2f * __logf(v.y);
    r.z = -0.2f * __logf(v.z);
    r.w = -0.2f * __logf(v.w);
    return r;
}

__global__ __launch_bounds__(256, 2) void always_minish_v3(
    const float* __restrict__ lower,
    const float* __restrict__ upper,
    float* __restrict__ out)
{
    const int lane  = threadIdx.x & 63;
    const int wv    = (blockIdx.x << 2) | (threadIdx.x >> 6);
    const int dq    = lane & 15;          // d-quad: channels 4*dq .. 4*dq+3
    const int sq    = lane >> 4;          // seq within group of 4
    const int g     = wv >> 8;            // seq group 0..7
    const int chunk = wv & (CHUNKS - 1);  // 0..255
    const int seq   = (g << 2) | sq;      // 0..31 = trace*16 + b
    const int tr    = seq >> 4;
    const int b     = seq & 15;

    const float* __restrict__ src =
        (tr ? upper : lower) + (size_t)b * TT * DD + dq * 4;
    float* __restrict__ dst = out + (size_t)seq * TT * DD + dq * 4;

    const int t0 = chunk * LCH;

    // ---- Issue ALL loads up front (48 independent dwordx4 per lane) ----
    float4 h[16], a[16], c[16];
    #pragma unroll
    for (int j = 0; j < 16; ++j) {
        int t = t0 - 16 + j;              // clamped halo (h0 broadcast pad)
        if (t < 0) t = 0;
        h[j] = *(const float4*)(src + (size_t)t * DD);
    }
    #pragma unroll
    for (int k = 0; k < 16; ++k)
        a[k] = *(const float4*)(src + (size_t)(t0 + k) * DD);
    #pragma unroll
    for (int k = 0; k < 16; ++k)
        c[k] = *(const float4*)(src + (size_t)(t0 + 16 + k) * DD);

    // ---- exp(-5x) elementwise ----
    #pragma unroll
    for (int j = 0; j < 16; ++j) h[j] = exp4n(h[j]);
    #pragma unroll
    for (int k = 0; k < 16; ++k) a[k] = exp4n(a[k]);
    #pragma unroll
    for (int k = 0; k < 16; ++k) c[k] = exp4n(c[k]);

    // ---- suffix sums of halo: h[j] = sum h[j..15] ----
    #pragma unroll
    for (int j = 14; j >= 0; --j) h[j] = add4(h[j], h[j + 1]);

    // ---- block 0: out[t0+k] from halo suffix + running prefix of a ----
    {
        float4 p = make_float4(0.f, 0.f, 0.f, 0.f);
        #pragma unroll
        for (int k = 0; k < 16; ++k) {
            p = add4(p, a[k]);
            const float4 w = (k < 15) ? add4(h[k + 1], p) : p;
            *(float4*)(dst + (size_t)(t0 + k) * DD) = mlog4(w);
        }
    }
    // suffix of block 0 in place
    #pragma unroll
    for (int j = 14; j >= 0; --j) a[j] = add4(a[j], a[j + 1]);

    // ---- block 1: out[t0+16+k] from a-suffix + running prefix of c ----
    {
        float4 p = make_float4(0.f, 0.f, 0.f, 0.f);
        #pragma unroll
        for (int k = 0; k < 16; ++k) {
            p = add4(p, c[k]);
            const float4 w = (k < 15) ? add4(a[k + 1], p) : p;
            *(float4*)(dst + (size_t)(t0 + 16 + k) * DD) = mlog4(w);
        }
    }
}

extern "C" void kernel_launch(void* const* d_in, const int* in_sizes, int n_in,
                              void* d_out, int out_size, void* d_ws, size_t ws_size,
                              hipStream_t stream)
{
    const float* lower = (const float*)d_in[0];
    const float* upper = (const float*)d_in[1];
    float* out = (float*)d_out;

    // waves = 8 seq-groups * 256 chunks = 2048 -> 512 blocks of 4 waves
    dim3 grid(512), block(256);
    hipLaunchKernelGGL(always_minish_v3, grid, block, 0, stream,
                       lower, upper, out);
}

// Round 5
// 117.941 us; speedup vs baseline: 1.0136x; 1.0136x over previous
//
#include <hip/hip_runtime.h>

// Always (smoothed-min sliding window, W=16) over [B,T,D] fp32, two traces.
// out[b,t,d] = -log( sum_{j=0..15} exp(-5 x[b, max(t-15+j,0), d]) ) / 5
//
// R5 = R4 with the nontemporal-store type fixed (clang ext_vector_type(4)
// instead of HIP_vector_type float4, which the builtin rejects).
//
// Design: LCH=16 per chunk; register state 32 float4 (~150 VGPR) -> 3
// waves/SIMD cap, grid = 4096 waves -> 12 resident waves/CU. All loads
// issued up front (32 independent dwordx4 / lane). Halo re-reads are
// L3-served. NT stores keep the 67 MB output from evicting input lines.

#define TT     8192
#define DD     64
#define BB     16
#define LCH    16            // t-steps per chunk (one aligned block)
#define CHUNKS (TT / LCH)    // 512

typedef float vfloat4 __attribute__((ext_vector_type(4)));

__device__ __forceinline__ float4 exp4n(float4 v) {
    float4 r;
    r.x = __expf(-5.0f * v.x);
    r.y = __expf(-5.0f * v.y);
    r.z = __expf(-5.0f * v.z);
    r.w = __expf(-5.0f * v.w);
    return r;
}
__device__ __forceinline__ float4 add4(float4 a, float4 b) {
    return make_float4(a.x + b.x, a.y + b.y, a.z + b.z, a.w + b.w);
}
__device__ __forceinline__ vfloat4 mlog4(float4 v) {
    vfloat4 r;
    r.x = -0.2f * __logf(v.x);
    r.y = -0.2f * __logf(v.y);
    r.z = -0.2f * __logf(v.z);
    r.w = -0.2f * __logf(v.w);
    return r;
}

__global__ __launch_bounds__(256, 3) void always_minish_v5(
    const float* __restrict__ lower,
    const float* __restrict__ upper,
    float* __restrict__ out)
{
    const int lane  = threadIdx.x & 63;
    const int wv    = (blockIdx.x << 2) | (threadIdx.x >> 6);
    const int dq    = lane & 15;           // d-quad: channels 4*dq .. 4*dq+3
    const int sq    = lane >> 4;           // seq within group of 4
    const int g     = wv >> 9;             // seq group 0..7
    const int chunk = wv & (CHUNKS - 1);   // 0..511
    const int seq   = (g << 2) | sq;       // 0..31 = trace*16 + b
    const int tr    = seq >> 4;
    const int b     = seq & 15;

    const float* __restrict__ src =
        (tr ? upper : lower) + (size_t)b * TT * DD + dq * 4;
    float* __restrict__ dst = out + (size_t)seq * TT * DD + dq * 4;

    const int t0 = chunk * LCH;

    // ---- Issue ALL 32 loads up front (independent dwordx4) ----
    float4 h[16], a[16];
    #pragma unroll
    for (int j = 0; j < 16; ++j) {
        int t = t0 - 16 + j;               // clamped halo = h0 broadcast pad
        if (t < 0) t = 0;
        h[j] = *(const float4*)(src + (size_t)t * DD);
    }
    #pragma unroll
    for (int k = 0; k < 16; ++k)
        a[k] = *(const float4*)(src + (size_t)(t0 + k) * DD);

    // ---- exp(-5x) ----
    #pragma unroll
    for (int j = 0; j < 16; ++j) h[j] = exp4n(h[j]);
    #pragma unroll
    for (int k = 0; k < 16; ++k) a[k] = exp4n(a[k]);

    // ---- suffix sums of halo: h[j] = sum h[j..15] ----
    #pragma unroll
    for (int j = 14; j >= 0; --j) h[j] = add4(h[j], h[j + 1]);

    // ---- out[t0+k] = -log(h_suffix[k+1] + prefix_a[k]) / 5, NT stores ----
    float4 p = make_float4(0.f, 0.f, 0.f, 0.f);
    #pragma unroll
    for (int k = 0; k < 16; ++k) {
        p = add4(p, a[k]);
        const float4 w = (k < 15) ? add4(h[k + 1], p) : p;
        __builtin_nontemporal_store(mlog4(w),
                                    (vfloat4*)(dst + (size_t)(t0 + k) * DD));
    }
}

extern "C" void kernel_launch(void* const* d_in, const int* in_sizes, int n_in,
                              void* d_out, int out_size, void* d_ws, size_t ws_size,
                              hipStream_t stream)
{
    const float* lower = (const float*)d_in[0];
    const float* upper = (const float*)d_in[1];
    float* out = (float*)d_out;

    // waves = 8 seq-groups * 512 chunks = 4096 -> 1024 blocks of 4 waves
    dim3 grid(1024), block(256);
    hipLaunchKernelGGL(always_minish_v5, grid, block, 0, stream,
                       lower, upper, out);
}

// Round 6
// 111.309 us; speedup vs baseline: 1.0739x; 1.0596x over previous
//
#include <hip/hip_runtime.h>

// Always (smoothed-min sliding window, W=16) over [B,T,D] fp32, two traces.
// out[b,t,d] = -log( sum_{j=0..15} exp(-5 x[b, max(t-15+j,0), d]) ) / 5
//
// R6 = R5 + __builtin_amdgcn_sched_barrier(0) between the load phase and
// the compute phase. R3/R5 showed VGPR_Count=48: the scheduler sank every
// load next to its use (6-deep load chains -> latency-serialized, 3.1 TB/s).
// The fence forces all 32 dwordx4 loads to issue before any VALU, keeping
// ~32 KB per wave in flight. launch_bounds(256,3) caps VGPR at 168 (state
// needs ~145, no spill).

#define TT     8192
#define DD     64
#define BB     16
#define LCH    16            // t-steps per chunk (one aligned block)
#define CHUNKS (TT / LCH)    // 512

typedef float vfloat4 __attribute__((ext_vector_type(4)));

__device__ __forceinline__ float4 exp4n(float4 v) {
    float4 r;
    r.x = __expf(-5.0f * v.x);
    r.y = __expf(-5.0f * v.y);
    r.z = __expf(-5.0f * v.z);
    r.w = __expf(-5.0f * v.w);
    return r;
}
__device__ __forceinline__ float4 add4(float4 a, float4 b) {
    return make_float4(a.x + b.x, a.y + b.y, a.z + b.z, a.w + b.w);
}
__device__ __forceinline__ vfloat4 mlog4(float4 v) {
    vfloat4 r;
    r.x = -0.2f * __logf(v.x);
    r.y = -0.2f * __logf(v.y);
    r.z = -0.2f * __logf(v.z);
    r.w = -0.2f * __logf(v.w);
    return r;
}

__global__ __launch_bounds__(256, 3) void always_minish_v6(
    const float* __restrict__ lower,
    const float* __restrict__ upper,
    float* __restrict__ out)
{
    const int lane  = threadIdx.x & 63;
    const int wv    = (blockIdx.x << 2) | (threadIdx.x >> 6);
    const int dq    = lane & 15;           // d-quad: channels 4*dq .. 4*dq+3
    const int sq    = lane >> 4;           // seq within group of 4
    const int g     = wv >> 9;             // seq group 0..7
    const int chunk = wv & (CHUNKS - 1);   // 0..511
    const int seq   = (g << 2) | sq;       // 0..31 = trace*16 + b
    const int tr    = seq >> 4;
    const int b     = seq & 15;

    const float* __restrict__ src =
        (tr ? upper : lower) + (size_t)b * TT * DD + dq * 4;
    float* __restrict__ dst = out + (size_t)seq * TT * DD + dq * 4;

    const int t0 = chunk * LCH;

    // ---- Load phase: 32 independent dwordx4, ALL issued before compute ----
    float4 h[16], a[16];
    #pragma unroll
    for (int j = 0; j < 16; ++j) {
        int t = t0 - 16 + j;               // clamped halo = h0 broadcast pad
        if (t < 0) t = 0;
        h[j] = *(const float4*)(src + (size_t)t * DD);
    }
    #pragma unroll
    for (int k = 0; k < 16; ++k)
        a[k] = *(const float4*)(src + (size_t)(t0 + k) * DD);

    // Hard scheduling fence: nothing moves across. Forces the 32 loads to
    // stay in the ISA ahead of all VALU (R5's allocator sank them -> 48 VGPR,
    // 6-deep MLP). After this point all loads are in flight.
    __builtin_amdgcn_sched_barrier(0);

    // ---- exp(-5x) ----
    #pragma unroll
    for (int j = 0; j < 16; ++j) h[j] = exp4n(h[j]);
    #pragma unroll
    for (int k = 0; k < 16; ++k) a[k] = exp4n(a[k]);

    // ---- suffix sums of halo: h[j] = sum h[j..15] ----
    #pragma unroll
    for (int j = 14; j >= 0; --j) h[j] = add4(h[j], h[j + 1]);

    // ---- out[t0+k] = -log(h_suffix[k+1] + prefix_a[k]) / 5, NT stores ----
    float4 p = make_float4(0.f, 0.f, 0.f, 0.f);
    #pragma unroll
    for (int k = 0; k < 16; ++k) {
        p = add4(p, a[k]);
        const float4 w = (k < 15) ? add4(h[k + 1], p) : p;
        __builtin_nontemporal_store(mlog4(w),
                                    (vfloat4*)(dst + (size_t)(t0 + k) * DD));
    }
}

extern "C" void kernel_launch(void* const* d_in, const int* in_sizes, int n_in,
                              void* d_out, int out_size, void* d_ws, size_t ws_size,
                              hipStream_t stream)
{
    const float* lower = (const float*)d_in[0];
    const float* upper = (const float*)d_in[1];
    float* out = (float*)d_out;

    // waves = 8 seq-groups * 512 chunks = 4096 -> 1024 blocks of 4 waves
    dim3 grid(1024), block(256);
    hipLaunchKernelGGL(always_minish_v6, grid, block, 0, stream,
                       lower, upper, out);
}